// Round 1
// baseline (348.180 us; speedup 1.0000x reference)
//
#include <hip/hip_runtime.h>
#include <hip/hip_bf16.h>

typedef short v8s __attribute__((ext_vector_type(8)));
typedef float v4f __attribute__((ext_vector_type(4)));

#define N_SUP 65536
#define N_QRY 262144
#define DIM   128
#define NC    64

__device__ __forceinline__ unsigned short f2bf(float f) {
    union { __hip_bfloat16 h; unsigned short u; } cv;
    cv.h = __float2bfloat16(f);
    return cv.u;
}

// ---------------------------------------------------------------------------
// Kernel A: per-block partial class sums (LDS accumulation, no global atomics)
// ---------------------------------------------------------------------------
__global__ __launch_bounds__(512)
void proto_accum(const float* __restrict__ sup, const int* __restrict__ lab,
                 float* __restrict__ part, float* __restrict__ cpart,
                 int rowsPerBlock) {
    __shared__ float acc[NC * DIM];
    __shared__ float cnt[NC];
    const int tid = threadIdx.x;
    for (int i = tid; i < NC * DIM; i += 512) acc[i] = 0.f;
    if (tid < NC) cnt[tid] = 0.f;
    __syncthreads();

    const int lane = tid & 63, wave = tid >> 6;
    const int perWave = rowsPerBlock >> 3;   // 8 waves per block
    int row = blockIdx.x * rowsPerBlock + wave * perWave;

    // software-pipelined: prefetch next row while accumulating current
    float2 v = *(const float2*)(sup + (size_t)row * DIM + lane * 2);
    int c = lab[row];
    for (int r = 0; r < perWave; ++r) {
        float2 vn = v; int cn = c;
        if (r + 1 < perWave) {
            vn = *(const float2*)(sup + (size_t)(row + 1) * DIM + lane * 2);
            cn = lab[row + 1];
        }
        atomicAdd(&acc[c * DIM + lane * 2],     v.x);
        atomicAdd(&acc[c * DIM + lane * 2 + 1], v.y);
        if (lane == 0) atomicAdd(&cnt[c], 1.f);
        v = vn; c = cn; ++row;
    }
    __syncthreads();

    float* pblk = part + (size_t)blockIdx.x * (NC * DIM);
    for (int i = tid; i < NC * DIM; i += 512) pblk[i] = acc[i];
    if (tid < NC) cpart[blockIdx.x * NC + tid] = cnt[tid];
}

// ---------------------------------------------------------------------------
// Kernel B: reduce partials -> bf16 prototypes [64][128] + ||p||^2 (f32)
// ---------------------------------------------------------------------------
__global__ __launch_bounds__(128)
void proto_finalize(const float* __restrict__ part, const float* __restrict__ cpart,
                    unsigned short* __restrict__ pb, float* __restrict__ pp,
                    int nblk) {
    const int c = blockIdx.x, t = threadIdx.x;
    float sum = 0.f;
    for (int b = 0; b < nblk; ++b)
        sum += part[(size_t)b * (NC * DIM) + c * DIM + t];

    __shared__ float red[128];
    float cv = (t < nblk) ? cpart[t * NC + c] : 0.f;
    red[t] = cv; __syncthreads();
    for (int s = 64; s > 0; s >>= 1) {
        if (t < s) red[t] += red[t + s];
        __syncthreads();
    }
    const float cnt = fmaxf(red[0], 1.f);
    __syncthreads();

    const float proto = sum / cnt;
    pb[c * DIM + t] = f2bf(proto);

    red[t] = proto * proto; __syncthreads();
    for (int s = 64; s > 0; s >>= 1) {
        if (t < s) red[t] += red[t + s];
        __syncthreads();
    }
    if (t == 0) pp[c] = red[0];
}

// ---------------------------------------------------------------------------
// Kernel C: distances via bf16 MFMA + fused row-softmax
// Per wave: 64 queries (4 m-steps of 16) x all 64 classes.
// A frag (16x32): lane holds Q[q0 + (l&15)][kk*32 + (l>>4)*8 + j], j=0..7
// B frag (32x16): lane holds P[n*16 + (l&15)][kk*32 + (l>>4)*8 + j]
// C/D: col = l&15, row = (l>>4)*4 + reg   [verified layout]
// ---------------------------------------------------------------------------
__global__ __launch_bounds__(256, 4)
void fsl_main(const float* __restrict__ qry, const unsigned short* __restrict__ pb,
              const float* __restrict__ pp, float* __restrict__ out) {
    const int tid  = threadIdx.x;
    const int lane = tid & 63, wave = tid >> 6;
    const int l15  = lane & 15, lg = lane >> 4;

    // B fragments: all 64 classes, K=128 -> 16 frags, loaded once (L2-hot)
    v8s B[4][4];
#pragma unroll
    for (int n = 0; n < 4; ++n)
#pragma unroll
        for (int kk = 0; kk < 4; ++kk)
            B[n][kk] = *(const v8s*)(pb + (n * 16 + l15) * DIM + kk * 32 + lg * 8);

    float ppn[4];
#pragma unroll
    for (int n = 0; n < 4; ++n) ppn[n] = pp[n * 16 + l15];

    const size_t qbase = (size_t)blockIdx.x * 256 + (size_t)wave * 64;

#pragma unroll 1
    for (int m = 0; m < 4; ++m) {
        const size_t q0 = qbase + m * 16;
        const float* rowp = qry + (q0 + l15) * DIM + lg * 8;

        float qq = 0.f;
        v8s A[4];
#pragma unroll
        for (int kk = 0; kk < 4; ++kk) {
            const float4 f0 = *(const float4*)(rowp + kk * 32);
            const float4 f1 = *(const float4*)(rowp + kk * 32 + 4);
            qq = fmaf(f0.x, f0.x, qq); qq = fmaf(f0.y, f0.y, qq);
            qq = fmaf(f0.z, f0.z, qq); qq = fmaf(f0.w, f0.w, qq);
            qq = fmaf(f1.x, f1.x, qq); qq = fmaf(f1.y, f1.y, qq);
            qq = fmaf(f1.z, f1.z, qq); qq = fmaf(f1.w, f1.w, qq);
            v8s a;
            a[0] = (short)f2bf(f0.x); a[1] = (short)f2bf(f0.y);
            a[2] = (short)f2bf(f0.z); a[3] = (short)f2bf(f0.w);
            a[4] = (short)f2bf(f1.x); a[5] = (short)f2bf(f1.y);
            a[6] = (short)f2bf(f1.z); a[7] = (short)f2bf(f1.w);
            A[kk] = a;
        }
        // full ||q||^2 for query row (l&15): sum the 4 k-slices across lane groups
        qq += __shfl_xor(qq, 16);
        qq += __shfl_xor(qq, 32);

        v4f acc[4];
#pragma unroll
        for (int n = 0; n < 4; ++n) { v4f z = {0.f, 0.f, 0.f, 0.f}; acc[n] = z; }
#pragma unroll
        for (int kk = 0; kk < 4; ++kk)
#pragma unroll
            for (int n = 0; n < 4; ++n)
                acc[n] = __builtin_amdgcn_mfma_f32_16x16x32_bf16(A[kk], B[n][kk], acc[n], 0, 0, 0);

        // softmax: query row q = q0 + lg*4 + j lives in the 16 lanes of group lg
#pragma unroll
        for (int j = 0; j < 4; ++j) {
            const float qqj = __shfl(qq, lg * 4 + j);
            float s0 = qqj + ppn[0] - 2.f * acc[0][j];
            float s1 = qqj + ppn[1] - 2.f * acc[1][j];
            float s2 = qqj + ppn[2] - 2.f * acc[2][j];
            float s3 = qqj + ppn[3] - 2.f * acc[3][j];
            s0 = -sqrtf(fmaxf(s0, 0.f)); s1 = -sqrtf(fmaxf(s1, 0.f));
            s2 = -sqrtf(fmaxf(s2, 0.f)); s3 = -sqrtf(fmaxf(s3, 0.f));
            float mx = fmaxf(fmaxf(s0, s1), fmaxf(s2, s3));
#pragma unroll
            for (int msk = 1; msk <= 8; msk <<= 1) mx = fmaxf(mx, __shfl_xor(mx, msk));
            float e0 = __expf(s0 - mx), e1 = __expf(s1 - mx);
            float e2 = __expf(s2 - mx), e3 = __expf(s3 - mx);
            float sum = (e0 + e1) + (e2 + e3);
#pragma unroll
            for (int msk = 1; msk <= 8; msk <<= 1) sum += __shfl_xor(sum, msk);
            const float inv = __fdividef(1.f, sum);
            float* orow = out + (q0 + (size_t)lg * 4 + j) * NC;
            orow[l15]      = e0 * inv;
            orow[16 + l15] = e1 * inv;
            orow[32 + l15] = e2 * inv;
            orow[48 + l15] = e3 * inv;
        }
    }
}

// ---------------------------------------------------------------------------
extern "C" void kernel_launch(void* const* d_in, const int* in_sizes, int n_in,
                              void* d_out, int out_size, void* d_ws, size_t ws_size,
                              hipStream_t stream) {
    const float* sup = (const float*)d_in[0];
    const int*   lab = (const int*)d_in[1];
    const float* qry = (const float*)d_in[2];
    float*       out = (float*)d_out;

    // pick partial-block count that fits the workspace
    int nblk = 128;
    auto need = [](int nb) -> size_t {
        return (size_t)nb * NC * DIM * 4 + (size_t)nb * NC * 4 + NC * DIM * 2 + NC * 4;
    };
    if (need(nblk) > ws_size) nblk = 64;
    if (need(nblk) > ws_size) nblk = 32;

    float*          part  = (float*)d_ws;
    float*          cpart = part + (size_t)nblk * NC * DIM;
    unsigned short* pbf   = (unsigned short*)((char*)d_ws +
                              (size_t)nblk * NC * DIM * 4 + (size_t)nblk * NC * 4);
    float*          pp    = (float*)((char*)pbf + NC * DIM * 2);

    const int rowsPerBlock = N_SUP / nblk;

    proto_accum<<<nblk, 512, 0, stream>>>(sup, lab, part, cpart, rowsPerBlock);
    proto_finalize<<<NC, 128, 0, stream>>>(part, cpart, pbf, pp, nblk);
    fsl_main<<<N_QRY / 256, 256, 0, stream>>>(qry, pbf, pp, out);
}

// Round 3
// 294.802 us; speedup vs baseline: 1.1811x; 1.1811x over previous
//
#include <hip/hip_runtime.h>
#include <hip/hip_bf16.h>

typedef short v8s __attribute__((ext_vector_type(8)));
typedef float v4f __attribute__((ext_vector_type(4)));

#define N_SUP 65536
#define N_QRY 262144
#define DIM   128
#define NC    64

__device__ __forceinline__ unsigned short f2bf(float f) {
    union { __hip_bfloat16 h; unsigned short u; } cv;
    cv.h = __float2bfloat16(f);
    return cv.u;
}

// ---------------------------------------------------------------------------
// Kernel A: prototype partial sums as a one-hot MFMA GEMM.
// 512 threads = 8 waves; wave w exclusively owns dim-tile dt=w (dims 16w..16w+15).
// Every wave iterates ALL rows of the block in 32-row chunks.
//   A-frag: lane holds onehot_T[class=l15+mt*16][k-slot=(lg,j)] (labels row kbase+j)
//   B-frag: lane holds emb[row kbase+j][dim=dt*16+l15]  (f32->bf16 scalar gather)
//   D: lane l reg r -> S[class=mt*16+lg*4+r][dim=dt*16+l15]   [fsl_main-proven layout]
// Counts: proven LDS-atomic method (wave 0, lanes 0..31 per chunk).
// No cross-wave merge needed: direct coalesced global stores of partials.
// ---------------------------------------------------------------------------
__global__ __launch_bounds__(512)
void proto_accum(const float* __restrict__ sup, const int* __restrict__ lab,
                 float* __restrict__ part, float* __restrict__ cpart,
                 int rowsPerBlock) {
    __shared__ float cnt_s[NC];
    const int tid  = threadIdx.x;
    const int lane = tid & 63, wave = tid >> 6;
    const int l15  = lane & 15, lg = lane >> 4;

    if (tid < NC) cnt_s[tid] = 0.f;
    __syncthreads();

    const int r0blk  = blockIdx.x * rowsPerBlock;
    const int nchunk = rowsPerBlock >> 5;
    const int dt     = wave;              // 8 waves x 16 dims = 128

    v4f acc[4];
#pragma unroll
    for (int mt = 0; mt < 4; ++mt) { v4f z = {0.f, 0.f, 0.f, 0.f}; acc[mt] = z; }

    for (int ch = 0; ch < nchunk; ++ch) {
        const int r0    = r0blk + ch * 32;
        const int kbase = r0 + lg * 8;
        const int4 L0 = *(const int4*)(lab + kbase);
        const int4 L1 = *(const int4*)(lab + kbase + 4);

        if (wave == 0 && lane < 32)
            atomicAdd(&cnt_s[lab[r0 + lane]], 1.f);

        v8s A[4];
#pragma unroll
        for (int mt = 0; mt < 4; ++mt) {
            const int c = mt * 16 + l15;
            v8s a;
            a[0] = (L0.x == c) ? (short)0x3F80 : (short)0;
            a[1] = (L0.y == c) ? (short)0x3F80 : (short)0;
            a[2] = (L0.z == c) ? (short)0x3F80 : (short)0;
            a[3] = (L0.w == c) ? (short)0x3F80 : (short)0;
            a[4] = (L1.x == c) ? (short)0x3F80 : (short)0;
            a[5] = (L1.y == c) ? (short)0x3F80 : (short)0;
            a[6] = (L1.z == c) ? (short)0x3F80 : (short)0;
            a[7] = (L1.w == c) ? (short)0x3F80 : (short)0;
            A[mt] = a;
        }

        const float* ep = sup + (size_t)kbase * DIM + dt * 16 + l15;
        v8s b;
#pragma unroll
        for (int j = 0; j < 8; ++j)
            b[j] = (short)f2bf(ep[j * DIM]);

#pragma unroll
        for (int mt = 0; mt < 4; ++mt)
            acc[mt] = __builtin_amdgcn_mfma_f32_16x16x32_bf16(A[mt], b, acc[mt], 0, 0, 0);
    }

    // wave owns dims dt*16..dt*16+15 exclusively -> plain stores, no atomics
    float* pblk = part + (size_t)blockIdx.x * (NC * DIM);
#pragma unroll
    for (int mt = 0; mt < 4; ++mt)
#pragma unroll
        for (int r = 0; r < 4; ++r)
            pblk[(mt * 16 + lg * 4 + r) * DIM + dt * 16 + l15] = acc[mt][r];

    __syncthreads();
    if (tid < NC) cpart[blockIdx.x * NC + tid] = cnt_s[tid];
}

// ---------------------------------------------------------------------------
// Kernel B: reduce partials -> bf16 protos + ||p||^2  (round-1-proven pattern)
// one block per class, 128 threads (t = dim); count summed redundantly per thread
// ---------------------------------------------------------------------------
__global__ __launch_bounds__(128)
void proto_finalize(const float* __restrict__ part, const float* __restrict__ cpart,
                    unsigned short* __restrict__ pb, float* __restrict__ pp,
                    int nblk) {
    const int c = blockIdx.x, t = threadIdx.x;
    float sum = 0.f;
#pragma unroll 4
    for (int b = 0; b < nblk; ++b)
        sum += part[(size_t)b * (NC * DIM) + c * DIM + t];

    float cntf = 0.f;
#pragma unroll 4
    for (int b = 0; b < nblk; ++b)
        cntf += cpart[b * NC + c];
    const float cnt = fmaxf(cntf, 1.f);

    const float proto = sum / cnt;
    pb[c * DIM + t] = f2bf(proto);

    __shared__ float red[128];
    red[t] = proto * proto;
    __syncthreads();
    for (int s = 64; s > 0; s >>= 1) {
        if (t < s) red[t] += red[t + s];
        __syncthreads();
    }
    if (t == 0) pp[c] = red[0];
}

// ---------------------------------------------------------------------------
// Kernel C: distances via bf16 MFMA + fused row-softmax (proven; only change:
// removed the min-waves launch-bounds hint that forced a 128-VGPR cap -> spills)
// ---------------------------------------------------------------------------
__global__ __launch_bounds__(256)
void fsl_main(const float* __restrict__ qry, const unsigned short* __restrict__ pb,
              const float* __restrict__ pp, float* __restrict__ out) {
    const int tid  = threadIdx.x;
    const int lane = tid & 63, wave = tid >> 6;
    const int l15  = lane & 15, lg = lane >> 4;

    v8s B[4][4];
#pragma unroll
    for (int n = 0; n < 4; ++n)
#pragma unroll
        for (int kk = 0; kk < 4; ++kk)
            B[n][kk] = *(const v8s*)(pb + (n * 16 + l15) * DIM + kk * 32 + lg * 8);

    float ppn[4];
#pragma unroll
    for (int n = 0; n < 4; ++n) ppn[n] = pp[n * 16 + l15];

    const size_t qbase = (size_t)blockIdx.x * 256 + (size_t)wave * 64;

#pragma unroll 1
    for (int m = 0; m < 4; ++m) {
        const size_t q0 = qbase + m * 16;
        const float* rowp = qry + (q0 + l15) * DIM + lg * 8;

        float qq = 0.f;
        v8s A[4];
#pragma unroll
        for (int kk = 0; kk < 4; ++kk) {
            const float4 f0 = *(const float4*)(rowp + kk * 32);
            const float4 f1 = *(const float4*)(rowp + kk * 32 + 4);
            qq = fmaf(f0.x, f0.x, qq); qq = fmaf(f0.y, f0.y, qq);
            qq = fmaf(f0.z, f0.z, qq); qq = fmaf(f0.w, f0.w, qq);
            qq = fmaf(f1.x, f1.x, qq); qq = fmaf(f1.y, f1.y, qq);
            qq = fmaf(f1.z, f1.z, qq); qq = fmaf(f1.w, f1.w, qq);
            v8s a;
            a[0] = (short)f2bf(f0.x); a[1] = (short)f2bf(f0.y);
            a[2] = (short)f2bf(f0.z); a[3] = (short)f2bf(f0.w);
            a[4] = (short)f2bf(f1.x); a[5] = (short)f2bf(f1.y);
            a[6] = (short)f2bf(f1.z); a[7] = (short)f2bf(f1.w);
            A[kk] = a;
        }
        qq += __shfl_xor(qq, 16);
        qq += __shfl_xor(qq, 32);

        v4f acc[4];
#pragma unroll
        for (int n = 0; n < 4; ++n) { v4f z = {0.f, 0.f, 0.f, 0.f}; acc[n] = z; }
#pragma unroll
        for (int kk = 0; kk < 4; ++kk)
#pragma unroll
            for (int n = 0; n < 4; ++n)
                acc[n] = __builtin_amdgcn_mfma_f32_16x16x32_bf16(A[kk], B[n][kk], acc[n], 0, 0, 0);

#pragma unroll
        for (int j = 0; j < 4; ++j) {
            const float qqj = __shfl(qq, lg * 4 + j);
            float s0 = qqj + ppn[0] - 2.f * acc[0][j];
            float s1 = qqj + ppn[1] - 2.f * acc[1][j];
            float s2 = qqj + ppn[2] - 2.f * acc[2][j];
            float s3 = qqj + ppn[3] - 2.f * acc[3][j];
            s0 = -sqrtf(fmaxf(s0, 0.f)); s1 = -sqrtf(fmaxf(s1, 0.f));
            s2 = -sqrtf(fmaxf(s2, 0.f)); s3 = -sqrtf(fmaxf(s3, 0.f));
            float mx = fmaxf(fmaxf(s0, s1), fmaxf(s2, s3));
#pragma unroll
            for (int msk = 1; msk <= 8; msk <<= 1) mx = fmaxf(mx, __shfl_xor(mx, msk));
            float e0 = __expf(s0 - mx), e1 = __expf(s1 - mx);
            float e2 = __expf(s2 - mx), e3 = __expf(s3 - mx);
            float sum = (e0 + e1) + (e2 + e3);
#pragma unroll
            for (int msk = 1; msk <= 8; msk <<= 1) sum += __shfl_xor(sum, msk);
            const float inv = __fdividef(1.f, sum);
            float* orow = out + (q0 + (size_t)lg * 4 + j) * NC;
            orow[l15]      = e0 * inv;
            orow[16 + l15] = e1 * inv;
            orow[32 + l15] = e2 * inv;
            orow[48 + l15] = e3 * inv;
        }
    }
}

// ---------------------------------------------------------------------------
extern "C" void kernel_launch(void* const* d_in, const int* in_sizes, int n_in,
                              void* d_out, int out_size, void* d_ws, size_t ws_size,
                              hipStream_t stream) {
    const float* sup = (const float*)d_in[0];
    const int*   lab = (const int*)d_in[1];
    const float* qry = (const float*)d_in[2];
    float*       out = (float*)d_out;

    auto need = [](int nb) -> size_t {
        return (size_t)nb * NC * DIM * 4 + (size_t)nb * NC * 4 + NC * DIM * 2 + NC * 4;
    };
    int nblk = 256;
    if (need(nblk) > ws_size) nblk = 128;
    if (need(nblk) > ws_size) nblk = 64;

    float*          part  = (float*)d_ws;
    float*          cpart = part + (size_t)nblk * NC * DIM;
    unsigned short* pbf   = (unsigned short*)((char*)d_ws +
                              (size_t)nblk * NC * DIM * 4 + (size_t)nblk * NC * 4);
    float*          pp    = (float*)((char*)pbf + NC * DIM * 2);

    const int rowsPerBlock = N_SUP / nblk;

    proto_accum<<<nblk, 512, 0, stream>>>(sup, lab, part, cpart, rowsPerBlock);
    proto_finalize<<<NC, 128, 0, stream>>>(part, cpart, pbf, pp, nblk);
    fsl_main<<<N_QRY / 256, 256, 0, stream>>>(qry, pbf, pp, out);
}

// Round 9
// 264.806 us; speedup vs baseline: 1.3148x; 1.1133x over previous
//
#include <hip/hip_runtime.h>
#include <hip/hip_bf16.h>

typedef short v8s __attribute__((ext_vector_type(8)));
typedef float v4f __attribute__((ext_vector_type(4)));

#define N_SUP 65536
#define N_QRY 262144
#define DIM   128
#define NC    64

__device__ __forceinline__ unsigned short f2bf(float f) {
    union { __hip_bfloat16 h; unsigned short u; } cv;
    cv.h = __float2bfloat16(f);
    return cv.u;
}

// ---------------------------------------------------------------------------
// Kernel A: prototype partial sums as a one-hot MFMA GEMM. (unchanged, proven)
// 512 threads = 8 waves; wave w owns dim-tile dt=w.
// ---------------------------------------------------------------------------
__global__ __launch_bounds__(512)
void proto_accum(const float* __restrict__ sup, const int* __restrict__ lab,
                 float* __restrict__ part, float* __restrict__ cpart,
                 int rowsPerBlock) {
    __shared__ float cnt_s[NC];
    const int tid  = threadIdx.x;
    const int lane = tid & 63, wave = tid >> 6;
    const int l15  = lane & 15, lg = lane >> 4;

    if (tid < NC) cnt_s[tid] = 0.f;
    __syncthreads();

    const int r0blk  = blockIdx.x * rowsPerBlock;
    const int nchunk = rowsPerBlock >> 5;
    const int dt     = wave;

    v4f acc[4];
#pragma unroll
    for (int mt = 0; mt < 4; ++mt) { v4f z = {0.f, 0.f, 0.f, 0.f}; acc[mt] = z; }

    for (int ch = 0; ch < nchunk; ++ch) {
        const int r0    = r0blk + ch * 32;
        const int kbase = r0 + lg * 8;
        const int4 L0 = *(const int4*)(lab + kbase);
        const int4 L1 = *(const int4*)(lab + kbase + 4);

        if (wave == 0 && lane < 32)
            atomicAdd(&cnt_s[lab[r0 + lane]], 1.f);

        v8s A[4];
#pragma unroll
        for (int mt = 0; mt < 4; ++mt) {
            const int c = mt * 16 + l15;
            v8s a;
            a[0] = (L0.x == c) ? (short)0x3F80 : (short)0;
            a[1] = (L0.y == c) ? (short)0x3F80 : (short)0;
            a[2] = (L0.z == c) ? (short)0x3F80 : (short)0;
            a[3] = (L0.w == c) ? (short)0x3F80 : (short)0;
            a[4] = (L1.x == c) ? (short)0x3F80 : (short)0;
            a[5] = (L1.y == c) ? (short)0x3F80 : (short)0;
            a[6] = (L1.z == c) ? (short)0x3F80 : (short)0;
            a[7] = (L1.w == c) ? (short)0x3F80 : (short)0;
            A[mt] = a;
        }

        const float* ep = sup + (size_t)kbase * DIM + dt * 16 + l15;
        v8s b;
#pragma unroll
        for (int j = 0; j < 8; ++j)
            b[j] = (short)f2bf(ep[j * DIM]);

#pragma unroll
        for (int mt = 0; mt < 4; ++mt)
            acc[mt] = __builtin_amdgcn_mfma_f32_16x16x32_bf16(A[mt], b, acc[mt], 0, 0, 0);
    }

    float* pblk = part + (size_t)blockIdx.x * (NC * DIM);
#pragma unroll
    for (int mt = 0; mt < 4; ++mt)
#pragma unroll
        for (int r = 0; r < 4; ++r)
            pblk[(mt * 16 + lg * 4 + r) * DIM + dt * 16 + l15] = acc[mt][r];

    __syncthreads();
    if (tid < NC) cpart[blockIdx.x * NC + tid] = cnt_s[tid];
}

// ---------------------------------------------------------------------------
// Kernel B: reduce partials -> bf16 protos + ||p||^2
// 512 threads: (s = t>>7) 4-way split of the nblk-long serial sum.
// ---------------------------------------------------------------------------
__global__ __launch_bounds__(512)
void proto_finalize(const float* __restrict__ part, const float* __restrict__ cpart,
                    unsigned short* __restrict__ pb, float* __restrict__ pp,
                    int nblk) {
    const int c = blockIdx.x, t = threadIdx.x;
    const int s = t >> 7, d = t & 127;
    const int per = nblk >> 2;

    float sum = 0.f;
    const float* pbase = part + (size_t)(s * per) * (NC * DIM) + c * DIM + d;
#pragma unroll 8
    for (int b = 0; b < per; ++b) sum += pbase[(size_t)b * (NC * DIM)];

    float cf = 0.f;
    const float* cbase = cpart + (size_t)(s * per) * NC + c;
#pragma unroll 8
    for (int b = 0; b < per; ++b) cf += cbase[(size_t)b * NC];

    __shared__ float red[512];
    __shared__ float red2[512];
    red[t] = sum; red2[t] = cf;
    __syncthreads();

    float proto = 0.f;
    if (t < 128) {
        const float tot = red[t] + red[t + 128] + red[t + 256] + red[t + 384];
        const float cnt = fmaxf(red2[t] + red2[t + 128] + red2[t + 256] + red2[t + 384], 1.f);
        proto = tot / cnt;
        pb[c * DIM + t] = f2bf(proto);
    }
    __syncthreads();
    red[t] = proto * proto;   // t>=128 contribute 0
    __syncthreads();
    for (int st = 256; st > 0; st >>= 1) {
        if (t < st) red[t] += red[t + st];
        __syncthreads();
    }
    if (t == 0) pp[c] = red[0];
}

// ---------------------------------------------------------------------------
// Kernel C: distances via SWAPPED-operand bf16 MFMA + lane-local softmax.
//   acc[n] = mfma(A = P-tile n, B = Q-tile)  ->  D[row=class][col=query]
//   D: col(l15) = query q0+l15, row = n*16 + lg*4 + r  (verified C/D layout)
// Each lane owns ONE query: 16 class-values in regs; softmax reduce is a
// local chain + 2 shfl_xor (16,32) for max and for sum (was 36 shfls).
// One m-step (16 queries) per wave; 4096 blocks for TLP.
// ---------------------------------------------------------------------------
__global__ __launch_bounds__(256)
void fsl_main(const float* __restrict__ qry, const unsigned short* __restrict__ pb,
              const float* __restrict__ pp, float* __restrict__ out) {
    const int tid  = threadIdx.x;
    const int lane = tid & 63, wave = tid >> 6;
    const int l15  = lane & 15, lg = lane >> 4;

    // A-operand: prototype fragments (class rows on l15, k on (lg,j))
    v8s PA[4][4];
#pragma unroll
    for (int n = 0; n < 4; ++n)
#pragma unroll
        for (int kk = 0; kk < 4; ++kk)
            PA[n][kk] = *(const v8s*)(pb + (n * 16 + l15) * DIM + kk * 32 + lg * 8);

    // ||p||^2 for this lane's 16 classes: class = n*16 + lg*4 + r
    v4f ppv[4];
#pragma unroll
    for (int n = 0; n < 4; ++n)
        ppv[n] = *(const v4f*)(pp + n * 16 + lg * 4);

    const size_t q0 = (size_t)blockIdx.x * 64 + (size_t)wave * 16;
    const float* rowp = qry + (q0 + l15) * DIM + lg * 8;

    // B-operand: query fragment (query cols on l15, k on (lg,j)) + ||q||^2
    float qq = 0.f;
    v8s QB[4];
#pragma unroll
    for (int kk = 0; kk < 4; ++kk) {
        const float4 f0 = *(const float4*)(rowp + kk * 32);
        const float4 f1 = *(const float4*)(rowp + kk * 32 + 4);
        qq = fmaf(f0.x, f0.x, qq); qq = fmaf(f0.y, f0.y, qq);
        qq = fmaf(f0.z, f0.z, qq); qq = fmaf(f0.w, f0.w, qq);
        qq = fmaf(f1.x, f1.x, qq); qq = fmaf(f1.y, f1.y, qq);
        qq = fmaf(f1.z, f1.z, qq); qq = fmaf(f1.w, f1.w, qq);
        v8s a;
        a[0] = (short)f2bf(f0.x); a[1] = (short)f2bf(f0.y);
        a[2] = (short)f2bf(f0.z); a[3] = (short)f2bf(f0.w);
        a[4] = (short)f2bf(f1.x); a[5] = (short)f2bf(f1.y);
        a[6] = (short)f2bf(f1.z); a[7] = (short)f2bf(f1.w);
        QB[kk] = a;
    }
    qq += __shfl_xor(qq, 16);
    qq += __shfl_xor(qq, 32);   // full ||q||^2 of query l15, in every lane

    v4f acc[4];
#pragma unroll
    for (int n = 0; n < 4; ++n) { v4f z = {0.f, 0.f, 0.f, 0.f}; acc[n] = z; }
#pragma unroll
    for (int kk = 0; kk < 4; ++kk)
#pragma unroll
        for (int n = 0; n < 4; ++n)
            acc[n] = __builtin_amdgcn_mfma_f32_16x16x32_bf16(PA[n][kk], QB[kk], acc[n], 0, 0, 0);

    // neg-distances for this lane's 16 classes
    float sv[4][4];
    float mx = -3.0e38f;
#pragma unroll
    for (int n = 0; n < 4; ++n)
#pragma unroll
        for (int r = 0; r < 4; ++r) {
            const float d2 = qq + ppv[n][r] - 2.f * acc[n][r];
            const float sd = -sqrtf(fmaxf(d2, 0.f));
            sv[n][r] = sd;
            mx = fmaxf(mx, sd);
        }
    mx = fmaxf(mx, __shfl_xor(mx, 16));
    mx = fmaxf(mx, __shfl_xor(mx, 32));

    float sum = 0.f;
    float ev[4][4];
#pragma unroll
    for (int n = 0; n < 4; ++n)
#pragma unroll
        for (int r = 0; r < 4; ++r) {
            const float e = __expf(sv[n][r] - mx);
            ev[n][r] = e;
            sum += e;
        }
    sum += __shfl_xor(sum, 16);
    sum += __shfl_xor(sum, 32);
    const float inv = __fdividef(1.f, sum);

    float* orow = out + (q0 + l15) * NC;
#pragma unroll
    for (int n = 0; n < 4; ++n) {
        v4f o;
        o[0] = ev[n][0] * inv; o[1] = ev[n][1] * inv;
        o[2] = ev[n][2] * inv; o[3] = ev[n][3] * inv;
        __builtin_nontemporal_store(o, (v4f*)(orow + n * 16 + lg * 4));
    }
}

// ---------------------------------------------------------------------------
extern "C" void kernel_launch(void* const* d_in, const int* in_sizes, int n_in,
                              void* d_out, int out_size, void* d_ws, size_t ws_size,
                              hipStream_t stream) {
    const float* sup = (const float*)d_in[0];
    const int*   lab = (const int*)d_in[1];
    const float* qry = (const float*)d_in[2];
    float*       out = (float*)d_out;

    auto need = [](int nb) -> size_t {
        return (size_t)nb * NC * DIM * 4 + (size_t)nb * NC * 4 + NC * DIM * 2 + NC * 4;
    };
    int nblk = 256;
    if (need(nblk) > ws_size) nblk = 128;
    if (need(nblk) > ws_size) nblk = 64;

    float*          part  = (float*)d_ws;
    float*          cpart = part + (size_t)nblk * NC * DIM;
    unsigned short* pbf   = (unsigned short*)((char*)d_ws +
                              (size_t)nblk * NC * DIM * 4 + (size_t)nblk * NC * 4);
    float*          pp    = (float*)((char*)pbf + NC * DIM * 2);

    const int rowsPerBlock = N_SUP / nblk;

    proto_accum<<<nblk, 512, 0, stream>>>(sup, lab, part, cpart, rowsPerBlock);
    proto_finalize<<<NC, 512, 0, stream>>>(part, cpart, pbf, pp, nblk);
    fsl_main<<<N_QRY / 64, 256, 0, stream>>>(qry, pbf, pp, out);
}